// Round 5
// baseline (303.436 us; speedup 1.0000x reference)
//
#include <hip/hip_runtime.h>
#include <hip/hip_bf16.h>

// cross_set_score, fused, no x-staging. Shapes: x[64,64,64,256] f32 (M=64, F=256).
// out[p,q] = out[q,p] = sum_h W2[h]*0.125*(sum_{a,b} relu(hA[a,h*64:]·hB[b,h*64:]))
//            / (nItem[p]*nItem[q]),  hA = x[p,q]@W1, hB = x[q,p]@W1.
// 2080 blocks = unordered pairs; 512 thr (8 waves). Wave w projects 16 rows of
// slice (w>>2) with A-frags loaded DIRECTLY from global x (f32->bf16 in reg) --
// no stage phase, loads interleave with MFMA. LDS holds only h (67.6 KiB) ->
// 2 blocks/CU = 16 waves/CU (4/SIMD). VGPR budgeted ~112 for the 128 cap.

#define NSET 64
#define MITEM 64
#define FFEAT 256

typedef float f32x4 __attribute__((ext_vector_type(4)));
typedef short bf16x8 __attribute__((ext_vector_type(8)));
typedef unsigned short u16;

__device__ __forceinline__ u16 f2bf(float f) {
    __bf16 b = (__bf16)f;
    return __builtin_bit_cast(u16, b);
}
__device__ __forceinline__ bf16x8 pack8(const float4& a, const float4& b) {
    bf16x8 r;
    r[0] = (short)f2bf(a.x); r[1] = (short)f2bf(a.y);
    r[2] = (short)f2bf(a.z); r[3] = (short)f2bf(a.w);
    r[4] = (short)f2bf(b.x); r[5] = (short)f2bf(b.y);
    r[6] = (short)f2bf(b.z); r[7] = (short)f2bf(b.w);
    return r;
}
__device__ __forceinline__ f32x4 mfma16(bf16x8 a, bf16x8 b, f32x4 c) {
    return __builtin_amdgcn_mfma_f32_16x16x32_bf16(a, b, c, 0, 0, 0);
}

// ---- prep: W1 [k=256][c=256] f32 -> W1T bf16 [c][k] (B-frags contiguous in k)
__global__ void prep_w1t_kernel(const float* __restrict__ w1, u16* __restrict__ w1t) {
    int c = blockIdx.x, k = threadIdx.x;
    w1t[c * 256 + k] = f2bf(w1[k * 256 + c]);
}

__global__ __launch_bounds__(512, 4) void fused_kernel(const float* __restrict__ x,
                                                       const u16* __restrict__ w1t,
                                                       const float* __restrict__ nItem,
                                                       const float* __restrict__ W2,
                                                       float* __restrict__ out) {
    // h only: [64 rows][264 cols] bf16, 528 B stride (16B-mult; benign bank alias)
    __shared__ u16 BUFA[MITEM][264];   // 33.8 KiB
    __shared__ u16 BUFB[MITEM][264];   // 33.8 KiB
    __shared__ float red[8];

    int p = 0, rem = blockIdx.x;
    while (rem >= NSET - p) { rem -= NSET - p; ++p; }
    const int q = p + rem;

    const float* xA = x + (size_t)(p * NSET + q) * (MITEM * FFEAT);
    const float* xB = x + (size_t)(q * NSET + p) * (MITEM * FFEAT);

    const int tid  = threadIdx.x;
    const int lane = tid & 63;
    const int wave = tid >> 6;          // 0..7
    const int ar   = lane & 15;
    const int kg   = lane >> 4;         // 0..3
    const int k0   = kg * 8;

    // ---------------- projection: wave owns 16 rows of one slice --------------
    const int rg = wave & 3;                       // row group
    const float* xs = (wave < 4) ? xA : xB;
    u16 (*BUF)[264] = (wave < 4) ? BUFA : BUFB;
    const float4* xrow = (const float4*)(xs + (size_t)(rg * 16 + ar) * FFEAT);

    f32x4 acc[16] = {};                            // 16 col-tiles x f32x4 = 64 VGPR
    float4 v0 = xrow[kg * 2], v1 = xrow[kg * 2 + 1];
#pragma unroll
    for (int kc = 0; kc < 8; ++kc) {
        bf16x8 a = pack8(v0, v1);
        if (kc < 7) {                              // 1-deep prefetch of next chunk
            v0 = xrow[(kc + 1) * 8 + kg * 2];
            v1 = xrow[(kc + 1) * 8 + kg * 2 + 1];
        }
#pragma unroll
        for (int u = 0; u < 16; u += 4) {          // 4 live B-frags at a time
            bf16x8 b0 = *(const bf16x8*)(w1t + (size_t)((u + 0) * 16 + ar) * 256 + kc * 32 + k0);
            bf16x8 b1 = *(const bf16x8*)(w1t + (size_t)((u + 1) * 16 + ar) * 256 + kc * 32 + k0);
            bf16x8 b2 = *(const bf16x8*)(w1t + (size_t)((u + 2) * 16 + ar) * 256 + kc * 32 + k0);
            bf16x8 b3 = *(const bf16x8*)(w1t + (size_t)((u + 3) * 16 + ar) * 256 + kc * 32 + k0);
            acc[u + 0] = mfma16(a, b0, acc[u + 0]);
            acc[u + 1] = mfma16(a, b1, acc[u + 1]);
            acc[u + 2] = mfma16(a, b2, acc[u + 2]);
            acc[u + 3] = mfma16(a, b3, acc[u + 3]);
        }
    }

    // write h fragments; C/D layout: col = lane&15, row = (lane>>4)*4 + j  [m89]
    const int rj = kg * 4;
#pragma unroll
    for (int u = 0; u < 16; ++u)
#pragma unroll
        for (int j = 0; j < 4; ++j)
            BUF[rg * 16 + rj + j][u * 16 + ar] = f2bf(acc[u][j]);
    __syncthreads();

    // ---------------- score: wave = (head hd, row-half rh) --------------------
    const int hd = wave & 3, rh = wave >> 2;
    const int hc = hd * 64;
    bf16x8 aS[2][2];
#pragma unroll
    for (int rt = 0; rt < 2; ++rt)
#pragma unroll
        for (int kk = 0; kk < 2; ++kk)
            aS[rt][kk] = *(const bf16x8*)&BUFA[rh * 32 + rt * 16 + ar][hc + kk * 32 + k0];

    float sum = 0.f;
#pragma unroll
    for (int bu = 0; bu < 4; ++bu) {
        bf16x8 b0 = *(const bf16x8*)&BUFB[bu * 16 + ar][hc + k0];
        bf16x8 b1 = *(const bf16x8*)&BUFB[bu * 16 + ar][hc + 32 + k0];
#pragma unroll
        for (int rt = 0; rt < 2; ++rt) {
            f32x4 c = {};
            c = mfma16(aS[rt][0], b0, c);
            c = mfma16(aS[rt][1], b1, c);   // full k=64 BEFORE relu
            sum += fmaxf(c[0], 0.f) + fmaxf(c[1], 0.f) +
                   fmaxf(c[2], 0.f) + fmaxf(c[3], 0.f);
        }
    }

    // ---------------- reduce + output -----------------------------------------
#pragma unroll
    for (int off = 32; off; off >>= 1) sum += __shfl_xor(sum, off);
    if (lane == 0) red[wave] = sum;
    __syncthreads();
    if (tid == 0) {
        const float nP = nItem[p], nQ = nItem[q];
        float v = 0.f;
#pragma unroll
        for (int h = 0; h < 4; ++h)
            v += ((((red[h] + red[h + 4]) * 0.125f) / nQ) / nP) * W2[h];
        out[p * NSET + q] = v;
        out[q * NSET + p] = v;
    }
}

extern "C" void kernel_launch(void* const* d_in, const int* in_sizes, int n_in,
                              void* d_out, int out_size, void* d_ws, size_t ws_size,
                              hipStream_t stream) {
    const float* x     = (const float*)d_in[0];
    const float* nItem = (const float*)d_in[1];
    const float* W1    = (const float*)d_in[2];
    const float* W2    = (const float*)d_in[3];
    float* out = (float*)d_out;

    u16* w1t = (u16*)d_ws;                 // 128 KiB
    if (ws_size < 131072) return;

    hipLaunchKernelGGL(prep_w1t_kernel, dim3(256), dim3(256), 0, stream, W1, w1t);
    hipLaunchKernelGGL(fused_kernel, dim3(2080), dim3(512), 0, stream,
                       x, w1t, nItem, W2, out);
}

// Round 6
// 238.177 us; speedup vs baseline: 1.2740x; 1.2740x over previous
//
#include <hip/hip_runtime.h>
#include <hip/hip_bf16.h>

// cross_set_score, fused + persistent software pipeline.
// x[64,64,64,256] f32. out[p,q]=out[q,p]= sum_h W2[h]*0.125*relu-sum(hA·hB^T)
//   / (nItem[p]*nItem[q]); hA=x[p,q]@W1, hB=x[q,p]@W1 (bf16 MFMA in-block).
// Grid 512 persistent blocks x 4-5 pairs; next pair's x loaded into regs
// DURING current pair's compute (A-slice before proj, B-slice before score).
// 512 thr (8 waves), LDS 68 KiB -> 2 blocks/CU = 16 waves/CU.

#define NSET 64
#define MITEM 64
#define FFEAT 256
#define NPAIR 2080
#define NBLK 512

typedef float f32x4 __attribute__((ext_vector_type(4)));
typedef short bf16x8 __attribute__((ext_vector_type(8)));
typedef unsigned short u16;
typedef u16 u16x4 __attribute__((ext_vector_type(4)));

__device__ __forceinline__ u16 f2bf(float f) {
    __bf16 b = (__bf16)f;
    return __builtin_bit_cast(u16, b);
}
__device__ __forceinline__ f32x4 mfma16(bf16x8 a, bf16x8 b, f32x4 c) {
    return __builtin_amdgcn_mfma_f32_16x16x32_bf16(a, b, c, 0, 0, 0);
}
__device__ __forceinline__ void decode_pair(int idx, int& p, int& q) {
    p = 0;
    while (idx >= NSET - p) { idx -= NSET - p; ++p; }
    q = p + idx;
}

// ---- prep: W1 [k=256][c=256] f32 -> W1T bf16 [c][k] (B-frags contiguous in k)
__global__ void prep_w1t_kernel(const float* __restrict__ w1, u16* __restrict__ w1t) {
    int c = blockIdx.x, k = threadIdx.x;
    w1t[c * 256 + k] = f2bf(w1[k * 256 + c]);
}

__global__ __launch_bounds__(512, 4) void fused_kernel(const float* __restrict__ x,
                                                       const u16* __restrict__ w1t,
                                                       const float* __restrict__ nItem,
                                                       const float* __restrict__ W2,
                                                       float* __restrict__ out) {
    __shared__ u16 BUFA[MITEM][264];   // 33.8 KiB: x_bf16 then h, 528 B stride
    __shared__ u16 BUFB[MITEM][264];   // 33.8 KiB
    __shared__ float red[8];

    const int tid  = threadIdx.x;
    const int lane = tid & 63;
    const int wave = tid >> 6;          // 0..7
    const int ar   = lane & 15;
    const int kg   = lane >> 4;
    const int k0   = kg * 8;

    int idx = blockIdx.x;               // first pair for this block

    // ---- prologue: issue coalesced loads of pair `idx` (wave covers 1 KiB/instr)
    float4 ra[8], rb[8];
    {
        int p, q; decode_pair(idx, p, q);
        const float* xA = x + (size_t)(p * NSET + q) * (MITEM * FFEAT);
        const float* xB = x + (size_t)(q * NSET + p) * (MITEM * FFEAT);
#pragma unroll
        for (int u = 0; u < 8; ++u) {
            ra[u] = *(const float4*)(xA + u * 2048 + tid * 4);
            rb[u] = *(const float4*)(xB + u * 2048 + tid * 4);
        }
    }

    for (;;) {
        int p, q; decode_pair(idx, p, q);

        // ---- convert staged regs -> LDS (bf16). ra/rb dead afterwards.
#pragma unroll
        for (int u = 0; u < 8; ++u) {
            const int f = u * 2048 + tid * 4;
            const int r = f >> 8, c = f & 255;
            u16x4 pa = { f2bf(ra[u].x), f2bf(ra[u].y), f2bf(ra[u].z), f2bf(ra[u].w) };
            u16x4 pb = { f2bf(rb[u].x), f2bf(rb[u].y), f2bf(rb[u].z), f2bf(rb[u].w) };
            *(u16x4*)&BUFA[r][c] = pa;
            *(u16x4*)&BUFB[r][c] = pb;
        }
        __syncthreads();

        // next-pair addresses (last iter: re-issue own pair — L3-hot, branchless)
        const int nidx = idx + NBLK;
        const bool last = nidx >= NPAIR;
        int lp, lq; decode_pair(last ? idx : nidx, lp, lq);
        const float* nxA = x + (size_t)(lp * NSET + lq) * (MITEM * FFEAT);
        const float* nxB = x + (size_t)(lq * NSET + lp) * (MITEM * FFEAT);

        // ---- issue next A-slice loads; they fly during proj ----
#pragma unroll
        for (int u = 0; u < 8; ++u) ra[u] = *(const float4*)(nxA + u * 2048 + tid * 4);
        __builtin_amdgcn_sched_barrier(0);

        // ---- projection: wave = (sel = wave>>2 slice, g = wave&3 64-col group)
        const int g = wave & 3;
        u16 (*BUF)[264] = (wave < 4) ? BUFA : BUFB;
        {
            f32x4 acc[4][4] = {};   // [row-tile][col-tile]
#pragma unroll
            for (int kc = 0; kc < 8; ++kc) {
                bf16x8 a[4];
#pragma unroll
                for (int rt = 0; rt < 4; ++rt)
                    a[rt] = *(const bf16x8*)&BUF[rt * 16 + ar][kc * 32 + k0];
#pragma unroll
                for (int u = 0; u < 4; ++u) {
                    bf16x8 bu = *(const bf16x8*)(w1t
                        + (size_t)(g * 64 + u * 16 + ar) * 256 + kc * 32 + k0);
#pragma unroll
                    for (int rt = 0; rt < 4; ++rt)
                        acc[rt][u] = mfma16(a[rt], bu, acc[rt][u]);
                }
            }
            __syncthreads();   // all x reads done before h overwrite

            // write h; C/D layout: col=lane&15, row=(lane>>4)*4+j  [m89]
            const int rj = kg * 4;
#pragma unroll
            for (int rt = 0; rt < 4; ++rt)
#pragma unroll
                for (int u = 0; u < 4; ++u) {
                    const int cc = g * 64 + u * 16 + ar;
#pragma unroll
                    for (int j = 0; j < 4; ++j)
                        BUF[rt * 16 + rj + j][cc] = f2bf(acc[rt][u][j]);
                }
        }
        __syncthreads();

        // ---- issue next B-slice loads; they fly during score ----
#pragma unroll
        for (int u = 0; u < 8; ++u) rb[u] = *(const float4*)(nxB + u * 2048 + tid * 4);
        __builtin_amdgcn_sched_barrier(0);

        // ---- score: wave = (head hd = wave&3, row-half rh = wave>>2) ----
        float sum = 0.f;
        {
            const int hd = wave & 3, rh = wave >> 2;
            const int hc = hd * 64;
            bf16x8 aS[2][2];
#pragma unroll
            for (int rt = 0; rt < 2; ++rt)
#pragma unroll
                for (int kk = 0; kk < 2; ++kk)
                    aS[rt][kk] = *(const bf16x8*)
                        &BUFA[rh * 32 + rt * 16 + ar][hc + kk * 32 + k0];
#pragma unroll
            for (int bu = 0; bu < 4; ++bu) {
                bf16x8 b0 = *(const bf16x8*)&BUFB[bu * 16 + ar][hc + k0];
                bf16x8 b1 = *(const bf16x8*)&BUFB[bu * 16 + ar][hc + 32 + k0];
#pragma unroll
                for (int rt = 0; rt < 2; ++rt) {
                    f32x4 c = {};
                    c = mfma16(aS[rt][0], b0, c);
                    c = mfma16(aS[rt][1], b1, c);   // full k=64 BEFORE relu
                    sum += fmaxf(c[0], 0.f) + fmaxf(c[1], 0.f) +
                           fmaxf(c[2], 0.f) + fmaxf(c[3], 0.f);
                }
            }
        }

        // ---- reduce + output ----
#pragma unroll
        for (int off = 32; off; off >>= 1) sum += __shfl_xor(sum, off);
        if (lane == 0) red[wave] = sum;
        __syncthreads();
        if (tid == 0) {
            const float nP = nItem[p], nQ = nItem[q];
            float v = 0.f;
#pragma unroll
            for (int h = 0; h < 4; ++h)
                v += ((((red[h] + red[h + 4]) * 0.125f) / nQ) / nP) * W2[h];
            out[p * NSET + q] = v;
            out[q * NSET + p] = v;
        }

        if (last) break;
        idx = nidx;
        __syncthreads();   // red[] + BUFA/BUFB reads done before next overwrite
    }
}

extern "C" void kernel_launch(void* const* d_in, const int* in_sizes, int n_in,
                              void* d_out, int out_size, void* d_ws, size_t ws_size,
                              hipStream_t stream) {
    const float* x     = (const float*)d_in[0];
    const float* nItem = (const float*)d_in[1];
    const float* W1    = (const float*)d_in[2];
    const float* W2    = (const float*)d_in[3];
    float* out = (float*)d_out;

    u16* w1t = (u16*)d_ws;                 // 128 KiB
    if (ws_size < 131072) return;

    hipLaunchKernelGGL(prep_w1t_kernel, dim3(256), dim3(256), 0, stream, W1, w1t);
    hipLaunchKernelGGL(fused_kernel, dim3(NBLK), dim3(512), 0, stream,
                       x, w1t, nItem, W2, out);
}

// Round 7
// 135.090 us; speedup vs baseline: 2.2462x; 1.7631x over previous
//
#include <hip/hip_runtime.h>
#include <hip/hip_bf16.h>

// cross_set_score, fused + persistent + LDS double-buffered pair pipeline.
// x[64,64,64,256] f32. out[p,q]=out[q,p]= sum_h W2[h]*0.125*relu-sum(hA·hB^T)
//   / (nItem[p]*nItem[q]); hA=x[p,q]@W1, hB=x[q,p]@W1 (bf16 MFMA in-block).
// 256 persistent blocks (1/CU) x 512 thr (8 waves), walking pairs bid+256k.
// Next pair's x is loaded (coalesced float4) at compute-phase top, lands in
// the OTHER LDS buffer after proj -> HBM streams continuously. No register
// residency across phases beyond the 16 staged float4 (fits 256-VGPR cap).

#define NSET 64
#define MITEM 64
#define FFEAT 256
#define NPAIR 2080
#define NBLK 256

typedef float f32x4 __attribute__((ext_vector_type(4)));
typedef short bf16x8 __attribute__((ext_vector_type(8)));
typedef unsigned short u16;
typedef u16 u16x4 __attribute__((ext_vector_type(4)));

__device__ __forceinline__ u16 f2bf(float f) {
    __bf16 b = (__bf16)f;
    return __builtin_bit_cast(u16, b);
}
__device__ __forceinline__ f32x4 mfma16(bf16x8 a, bf16x8 b, f32x4 c) {
    return __builtin_amdgcn_mfma_f32_16x16x32_bf16(a, b, c, 0, 0, 0);
}
__device__ __forceinline__ void decode_pair(int idx, int& p, int& q) {
    p = 0;
    while (idx >= NSET - p) { idx -= NSET - p; ++p; }
    q = p + idx;
}

// ---- prep: W1 [k=256][c=256] f32 -> W1T bf16 [c][k] (B-frags contiguous in k)
__global__ void prep_w1t_kernel(const float* __restrict__ w1, u16* __restrict__ w1t) {
    int c = blockIdx.x, k = threadIdx.x;
    w1t[c * 256 + k] = f2bf(w1[k * 256 + c]);
}

__global__ __launch_bounds__(512, 2) void fused_kernel(const float* __restrict__ x,
                                                       const u16* __restrict__ w1t,
                                                       const float* __restrict__ nItem,
                                                       const float* __restrict__ W2,
                                                       float* __restrict__ out) {
    // [dbuf][slice A/B][64 rows][264 cols] bf16 (528 B stride, benign 2-way alias)
    __shared__ u16 BUF[2][2][MITEM][264];   // 135.2 KiB -> 1 block/CU
    __shared__ float red[8];

    const int tid  = threadIdx.x;
    const int lane = tid & 63;
    const int wave = tid >> 6;          // 0..7
    const int ar   = lane & 15;
    const int kg   = lane >> 4;
    const int k0   = kg * 8;

    int idx = blockIdx.x;
    int b = 0;

    // ---- prologue: stage pair `idx` into buffer 0 ----------------------------
    {
        int p, q; decode_pair(idx, p, q);
        const float* xA = x + (size_t)(p * NSET + q) * (MITEM * FFEAT);
        const float* xB = x + (size_t)(q * NSET + p) * (MITEM * FFEAT);
        float4 ra[8], rb[8];
#pragma unroll
        for (int u = 0; u < 8; ++u) {
            ra[u] = *(const float4*)(xA + u * 2048 + tid * 4);
            rb[u] = *(const float4*)(xB + u * 2048 + tid * 4);
        }
#pragma unroll
        for (int u = 0; u < 8; ++u) {
            const int f = u * 2048 + tid * 4;
            const int r = f >> 8, c = f & 255;
            u16x4 pa = { f2bf(ra[u].x), f2bf(ra[u].y), f2bf(ra[u].z), f2bf(ra[u].w) };
            u16x4 pb = { f2bf(rb[u].x), f2bf(rb[u].y), f2bf(rb[u].z), f2bf(rb[u].w) };
            *(u16x4*)&BUF[0][0][r][c] = pa;
            *(u16x4*)&BUF[0][1][r][c] = pb;
        }
    }

    for (;;) {
        __syncthreads();   // staged buf b visible; prior readers of buf b done
        int p, q; decode_pair(idx, p, q);

        // ---- issue next pair's loads (branchless: last iter reloads own, L3-hot)
        const int nidx = idx + NBLK;
        const bool last = nidx >= NPAIR;
        int np_, nq_; decode_pair(last ? idx : nidx, np_, nq_);
        const float* nxA = x + (size_t)(np_ * NSET + nq_) * (MITEM * FFEAT);
        const float* nxB = x + (size_t)(nq_ * NSET + np_) * (MITEM * FFEAT);
        float4 ra[8], rb[8];
#pragma unroll
        for (int u = 0; u < 8; ++u) {
            ra[u] = *(const float4*)(nxA + u * 2048 + tid * 4);
            rb[u] = *(const float4*)(nxB + u * 2048 + tid * 4);
        }
        __builtin_amdgcn_sched_barrier(0);   // pin load issue before proj

        // ---- projection: wave = (sel = wave>>2 slice, g = wave&3 64-col group)
        const int g   = wave & 3;
        const int sel = wave >> 2;
        u16 (*XB)[264] = BUF[b][sel];
        f32x4 acc[4][4] = {};   // [row-tile][col-tile]
#pragma unroll
        for (int kc = 0; kc < 8; ++kc) {
            bf16x8 a[4];
#pragma unroll
            for (int rt = 0; rt < 4; ++rt)
                a[rt] = *(const bf16x8*)&XB[rt * 16 + ar][kc * 32 + k0];
#pragma unroll
            for (int u = 0; u < 4; ++u) {
                bf16x8 bu = *(const bf16x8*)(w1t
                    + (size_t)(g * 64 + u * 16 + ar) * 256 + kc * 32 + k0);
#pragma unroll
                for (int rt = 0; rt < 4; ++rt)
                    acc[rt][u] = mfma16(a[rt], bu, acc[rt][u]);
            }
        }
        __syncthreads();   // all x reads of buf b done before h overwrite

        // ---- write h over buf b; C/D layout col=lane&15, row=(lane>>4)*4+j [m89]
        const int rj = kg * 4;
#pragma unroll
        for (int rt = 0; rt < 4; ++rt)
#pragma unroll
            for (int u = 0; u < 4; ++u) {
                const int cc = g * 64 + u * 16 + ar;
#pragma unroll
                for (int j = 0; j < 4; ++j)
                    XB[rt * 16 + rj + j][cc] = f2bf(acc[rt][u][j]);
            }

        // ---- drain staged regs -> other buffer (loads have been flying) ------
#pragma unroll
        for (int u = 0; u < 8; ++u) {
            const int f = u * 2048 + tid * 4;
            const int r = f >> 8, c = f & 255;
            u16x4 pa = { f2bf(ra[u].x), f2bf(ra[u].y), f2bf(ra[u].z), f2bf(ra[u].w) };
            u16x4 pb = { f2bf(rb[u].x), f2bf(rb[u].y), f2bf(rb[u].z), f2bf(rb[u].w) };
            *(u16x4*)&BUF[b ^ 1][0][r][c] = pa;
            *(u16x4*)&BUF[b ^ 1][1][r][c] = pb;
        }
        __syncthreads();   // h visible

        // ---- score: wave = (head hd = wave&3, row-half rh = wave>>2) ---------
        float sum = 0.f;
        {
            const int hd = wave & 3, rh = wave >> 2;
            const int hc = hd * 64;
            bf16x8 aS[2][2];
#pragma unroll
            for (int rt = 0; rt < 2; ++rt)
#pragma unroll
                for (int kk = 0; kk < 2; ++kk)
                    aS[rt][kk] = *(const bf16x8*)
                        &BUF[b][0][rh * 32 + rt * 16 + ar][hc + kk * 32 + k0];
#pragma unroll
            for (int bu = 0; bu < 4; ++bu) {
                bf16x8 b0 = *(const bf16x8*)&BUF[b][1][bu * 16 + ar][hc + k0];
                bf16x8 b1 = *(const bf16x8*)&BUF[b][1][bu * 16 + ar][hc + 32 + k0];
#pragma unroll
                for (int rt = 0; rt < 2; ++rt) {
                    f32x4 c = {};
                    c = mfma16(aS[rt][0], b0, c);
                    c = mfma16(aS[rt][1], b1, c);   // full k=64 BEFORE relu
                    sum += fmaxf(c[0], 0.f) + fmaxf(c[1], 0.f) +
                           fmaxf(c[2], 0.f) + fmaxf(c[3], 0.f);
                }
            }
        }

        // ---- reduce + output -------------------------------------------------
#pragma unroll
        for (int off = 32; off; off >>= 1) sum += __shfl_xor(sum, off);
        if (lane == 0) red[wave] = sum;
        __syncthreads();
        if (tid == 0) {
            const float nP = nItem[p], nQ = nItem[q];
            float v = 0.f;
#pragma unroll
            for (int h = 0; h < 4; ++h)
                v += ((((red[h] + red[h + 4]) * 0.125f) / nQ) / nP) * W2[h];
            out[p * NSET + q] = v;
            out[q * NSET + p] = v;
        }

        if (last) break;
        idx = nidx;
        b ^= 1;
    }
}

extern "C" void kernel_launch(void* const* d_in, const int* in_sizes, int n_in,
                              void* d_out, int out_size, void* d_ws, size_t ws_size,
                              hipStream_t stream) {
    const float* x     = (const float*)d_in[0];
    const float* nItem = (const float*)d_in[1];
    const float* W1    = (const float*)d_in[2];
    const float* W2    = (const float*)d_in[3];
    float* out = (float*)d_out;

    u16* w1t = (u16*)d_ws;                 // 128 KiB
    if (ws_size < 131072) return;

    hipLaunchKernelGGL(prep_w1t_kernel, dim3(256), dim3(256), 0, stream, W1, w1t);
    hipLaunchKernelGGL(fused_kernel, dim3(NBLK), dim3(512), 0, stream,
                       x, w1t, nItem, W2, out);
}